// Round 9
// baseline (175.402 us; speedup 1.0000x reference)
//
#include <hip/hip_runtime.h>

// DualAttention: B=4, N=1024, QN=512, C=1024, H=16, D=64
// bf16 MFMA everywhere, fp32 softmax (log2-domain). GEMM epilogues emit V
// pre-transposed. Big GEMMs: 256x256 tile, BK=64, 8-phase schedule, counted
// vmcnt(4). Attention: swapped QK^T, in-register softmax, T15 pipeline,
// counted-vmcnt stage-ahead-2 prefetch (K,V triple-buffered, no full drain).

using bf16 = __bf16;
typedef __bf16 bf16x4 __attribute__((ext_vector_type(4)));
typedef __bf16 bf16x8 __attribute__((ext_vector_type(8)));
typedef float  f32x4  __attribute__((ext_vector_type(4)));
typedef float  f32x16 __attribute__((ext_vector_type(16)));
typedef unsigned int u32x4 __attribute__((ext_vector_type(4)));

#define MFMA16(a, b, c) __builtin_amdgcn_mfma_f32_16x16x32_bf16((a), (b), (c), 0, 0, 0)
#define MFMA32(a, b, c) __builtin_amdgcn_mfma_f32_32x32x16_bf16((a), (b), (c), 0, 0, 0)

// XOR swizzle for 128B LDS rows (8 granules of 16B).
__device__ __forceinline__ int swz128(int row) { return ((row ^ (row >> 3)) & 7) << 4; }

__device__ __forceinline__ void gl_lds16(const void* g, void* l) {
  __builtin_amdgcn_global_load_lds(
      (const __attribute__((address_space(1))) unsigned int*)g,
      (__attribute__((address_space(3))) unsigned int*)l, 16, 0, 0);
}

__device__ __forceinline__ unsigned pack2(float a, float b) {
  unsigned short ua = __builtin_bit_cast(unsigned short, (bf16)a);
  unsigned short ub = __builtin_bit_cast(unsigned short, (bf16)b);
  return (unsigned)ua | ((unsigned)ub << 16);
}

__device__ __forceinline__ float exp2_fast(float x) {  // v_exp_f32 IS 2^x
  float r;
  asm("v_exp_f32 %0, %1" : "=v"(r) : "v"(x));
  return r;
}

#define WAITV(N) asm volatile("s_waitcnt vmcnt(" #N ")" ::: "memory")
#define LGKM0()  asm volatile("s_waitcnt lgkmcnt(0)" ::: "memory")
#define SCHED0() __builtin_amdgcn_sched_barrier(0)
#define RAW_BAR() do { __builtin_amdgcn_s_barrier(); asm volatile("" ::: "memory"); } while (0)

// ---------------------------------------------------------------- fused cast fp32->bf16
// ws layout (elements, M = 1<<20): xb@0(4M) qb@4M(2M) wqkv@6M(3M) wkv@9M(2M)
// wqlin@11M(3M) wproj@14M(1M) wqproj@15M(1M). Must match kernel_launch.
__global__ void k_cast_all(const float* __restrict__ s0, const float* __restrict__ s1,
                           const float* __restrict__ s2, const float* __restrict__ s3,
                           const float* __restrict__ s4, const float* __restrict__ s5,
                           const float* __restrict__ s6, bf16* __restrict__ dst) {
  constexpr size_t MM = 1u << 20;
  constexpr size_t o1 = 4 * MM, o2 = 6 * MM, o3 = 9 * MM, o4 = 11 * MM,
                   o5 = 14 * MM, o6 = 15 * MM, total = 16 * MM;
  size_t stride = (size_t)gridDim.x * blockDim.x * 8;
  for (size_t i = ((size_t)blockIdx.x * blockDim.x + threadIdx.x) * 8; i < total; i += stride) {
    const float* s; size_t loc;
    if (i < o1)      { s = s0; loc = i; }
    else if (i < o2) { s = s1; loc = i - o1; }
    else if (i < o3) { s = s2; loc = i - o2; }
    else if (i < o4) { s = s3; loc = i - o3; }
    else if (i < o5) { s = s4; loc = i - o4; }
    else if (i < o6) { s = s5; loc = i - o5; }
    else             { s = s6; loc = i - o6; }
    float4 a = *(const float4*)(s + loc);
    float4 b = *(const float4*)(s + loc + 4);
    bf16x8 o;
    o[0] = (bf16)a.x; o[1] = (bf16)a.y; o[2] = (bf16)a.z; o[3] = (bf16)a.w;
    o[4] = (bf16)b.x; o[5] = (bf16)b.y; o[6] = (bf16)b.z; o[7] = (bf16)b.w;
    *(bf16x8*)(dst + i) = o;
  }
}

// ---------------------------------------------------------------- big grouped GEMM (8-phase)
// 256x256 tile, BK=64 (2 k-halves of 32), 512 threads (8 waves 2Mx4N).
// LDS: A,B each [2 buf][2 kh][256 rows][32 k] bf16 = 64 KB -> 128 KB total.
// Per tile j: 4 phases; each {ds_read frags | stage half-tile} -> barrier ->
// lgkmcnt(0) -> 16 MFMA -> barrier. Boundary: vmcnt(4).
// Groups: bid [0,320): XKV (xb x [wqkv|wkv], M=4096 N=5120);
//         bid [320,416): qlin (qb x wqlin, M=2048 N=3072).
__global__ __launch_bounds__(512)
void k_gemm_big(const bf16* __restrict__ xb, const bf16* __restrict__ qb,
                const bf16* __restrict__ wqkvb, const bf16* __restrict__ wqlinb,
                bf16* __restrict__ XK, bf16* __restrict__ VTs, bf16* __restrict__ VT0,
                bf16* __restrict__ QQK, bf16* __restrict__ VTq) {
  constexpr int K = 1024, NT = 16;
  __shared__ bf16 As[2 * 2 * 256 * 32];
  __shared__ bf16 Bs[2 * 2 * 256 * 32];
  const int tid = threadIdx.x;
  const int lane = tid & 63, w = tid >> 6;
  const int wm = w >> 2, wn = w & 3;
  const int r0 = lane & 15, kg = lane >> 4;
  const int bid = ((int)blockIdx.x & 7) * 52 + ((int)blockIdx.x >> 3);  // 416 = 8*52
  int grp, tm, tn;
  const bf16 *Ap, *Bp;
  if (bid < 320) { grp = 0; tm = (bid / 20) * 256; tn = (bid % 20) * 256; Ap = xb; Bp = wqkvb; }
  else { grp = 1; int t = bid - 320; tm = (t / 12) * 256; tn = (t % 12) * 256; Ap = qb; Bp = wqlinb; }

  auto stage = [&](int T, int mat, int kh) {
    const bf16* src = mat ? Bp : Ap;
    const int t0 = mat ? tn : tm;
    char* base = (char*)(mat ? (void*)Bs : (void*)As) + (((T & 1) * 2 + kh) << 14);
#pragma unroll
    for (int i = 0; i < 2; i++) {
      int c = i * 512 + tid;
      int row = c >> 2, g = c & 3;
      int sg = (g ^ ((row >> 1) & 3)) * 8;  // pre-swizzled source granule
      gl_lds16(src + (size_t)(t0 + row) * K + T * 64 + kh * 32 + sg, base + c * 16);
    }
  };
  auto ldA = [&](int bi, int kh, int row) -> bf16x8 {
    return *(const bf16x8*)((const char*)As + ((bi * 2 + kh) << 14) + row * 64 +
                            ((kg ^ ((row >> 1) & 3)) << 4));
  };
  auto ldB = [&](int bi, int kh, int row) -> bf16x8 {
    return *(const bf16x8*)((const char*)Bs + ((bi * 2 + kh) << 14) + row * 64 +
                            ((kg ^ ((row >> 1) & 3)) << 4));
  };

  f32x4 acc[8][4] = {};

  stage(0, 0, 0); stage(0, 1, 0); stage(0, 0, 1); stage(0, 1, 1);
  stage(1, 0, 0); stage(1, 1, 0);
  WAITV(4);
  RAW_BAR();

  for (int j = 0; j < NT; ++j) {
    const int bi = j & 1;
    bf16x8 af[4], bfk[4];
    // ---- phase 1: (mh0, kh0)
#pragma unroll
    for (int i = 0; i < 4; i++) af[i] = ldA(bi, 0, wm * 128 + i * 16 + r0);
#pragma unroll
    for (int nf = 0; nf < 4; nf++) bfk[nf] = ldB(bi, 0, wn * 64 + nf * 16 + r0);
    if (j + 1 < NT) stage(j + 1, 0, 1);
    RAW_BAR(); LGKM0(); SCHED0();
    __builtin_amdgcn_s_setprio(1);
#pragma unroll
    for (int i = 0; i < 4; i++)
#pragma unroll
      for (int nf = 0; nf < 4; nf++) acc[i][nf] = MFMA16(af[i], bfk[nf], acc[i][nf]);
    __builtin_amdgcn_s_setprio(0);
    RAW_BAR();
    // ---- phase 2: (mh1, kh0)
#pragma unroll
    for (int i = 0; i < 4; i++) af[i] = ldA(bi, 0, wm * 128 + 64 + i * 16 + r0);
    if (j + 1 < NT) stage(j + 1, 1, 1);
    RAW_BAR(); LGKM0(); SCHED0();
    __builtin_amdgcn_s_setprio(1);
#pragma unroll
    for (int i = 0; i < 4; i++)
#pragma unroll
      for (int nf = 0; nf < 4; nf++) acc[4 + i][nf] = MFMA16(af[i], bfk[nf], acc[4 + i][nf]);
    __builtin_amdgcn_s_setprio(0);
    RAW_BAR();
    // ---- phase 3: (mh0, kh1)
#pragma unroll
    for (int i = 0; i < 4; i++) af[i] = ldA(bi, 1, wm * 128 + i * 16 + r0);
#pragma unroll
    for (int nf = 0; nf < 4; nf++) bfk[nf] = ldB(bi, 1, wn * 64 + nf * 16 + r0);
    if (j + 2 < NT) stage(j + 2, 0, 0);
    RAW_BAR(); LGKM0(); SCHED0();
    __builtin_amdgcn_s_setprio(1);
#pragma unroll
    for (int i = 0; i < 4; i++)
#pragma unroll
      for (int nf = 0; nf < 4; nf++) acc[i][nf] = MFMA16(af[i], bfk[nf], acc[i][nf]);
    __builtin_amdgcn_s_setprio(0);
    RAW_BAR();
    // ---- phase 4: (mh1, kh1)
#pragma unroll
    for (int i = 0; i < 4; i++) af[i] = ldA(bi, 1, wm * 128 + 64 + i * 16 + r0);
    if (j + 2 < NT) stage(j + 2, 1, 0);
    RAW_BAR(); LGKM0(); SCHED0();
    __builtin_amdgcn_s_setprio(1);
#pragma unroll
    for (int i = 0; i < 4; i++)
#pragma unroll
      for (int nf = 0; nf < 4; nf++) acc[4 + i][nf] = MFMA16(af[i], bfk[nf], acc[4 + i][nf]);
    __builtin_amdgcn_s_setprio(0);
    if (j < NT - 2) { WAITV(4); } else { WAITV(0); }
    RAW_BAR();
  }

  // ---------------- epilogue (tn/tm uniform per block; ranges never straddle)
#pragma unroll
  for (int mf = 0; mf < 8; mf++) {
    const int rowb = tm + wm * 128 + mf * 16 + kg * 4;  // 4 consecutive rows (j)
#pragma unroll
    for (int nf = 0; nf < 4; nf++) {
      const int coln = tn + wn * 64 + nf * 16 + r0;
      bool rm; int rmcol = coln, vbase = 0, tokb = 10, rs_ = 3072;
      bf16* vt = VTs;
      bf16* rmp = XK;
      if (grp == 0) {
        if (tn < 2048)      { rm = true; }
        else if (tn < 3072) { rm = false; vbase = 2048; vt = VTs; }
        else if (tn < 4096) { rm = true; rmcol = coln - 1024; }
        else                { rm = false; vbase = 4096; vt = VT0; }
      } else {
        rs_ = 2048; tokb = 9; rmp = QQK;
        if (tn < 2048) { rm = true; }
        else           { rm = false; vbase = 2048; vt = VTq; }
      }
      if (rm) {
#pragma unroll
        for (int j = 0; j < 4; j++)
          rmp[(size_t)(rowb + j) * rs_ + rmcol] = (bf16)acc[mf][nf][j];
      } else {
        int dg = coln - vbase, h_ = dg >> 6, dd = dg & 63;
        int bq = rowb >> tokb, tok = rowb & ((1 << tokb) - 1);
        bf16x4 wv;
#pragma unroll
        for (int j = 0; j < 4; j++) wv[j] = (bf16)acc[mf][nf][j];
        *(bf16x4*)(vt + (((size_t)((bq * 16 + h_) * 64 + dd)) << tokb) + tok) = wv;
      }
    }
  }
}

// ---------------------------------------------------------------- proj GEMM (128x128, proven)
// C[6144,1024] = [xat|qat] x [w_proj|w_qproj]^T + bias, fp32 out to d_out.
__global__ __launch_bounds__(256)
void k_gemm_proj(const bf16* __restrict__ A, const bf16* __restrict__ B0,
                 const bf16* __restrict__ B1, const float* __restrict__ bias0,
                 const float* __restrict__ bias1, float* __restrict__ OUT) {
  constexpr int K = 1024, N = 1024;
  __shared__ bf16 As[128 * 64];
  __shared__ bf16 Bs[128 * 64];
  const int tid = threadIdx.x;
  const int lane = tid & 63, w = tid >> 6;
  const int wr = w >> 1, wc = w & 1;
  const int nbx = N / 128;
  const int bid = ((int)blockIdx.x & 7) * ((int)gridDim.x >> 3) + ((int)blockIdx.x >> 3);
  const int tm = (bid / nbx) * 128, tn = (bid % nbx) * 128;
  const int r0 = lane & 15, kg = lane >> 4;
  const bf16* Bp = (tm < 4096) ? B0 : B1;
  const float* bias = (tm < 4096) ? bias0 : bias1;
  f32x4 acc[4][4] = {};
  for (int kk = 0; kk < K; kk += 64) {
#pragma unroll
    for (int i = 0; i < 4; i++) {
      int c = i * 256 + tid;
      int row = c >> 3, kb = c & 7;
      int sb = (kb ^ ((row ^ (row >> 3)) & 7)) * 8;
      gl_lds16(A + (size_t)(tm + row) * K + kk + sb, (char*)As + c * 16);
      gl_lds16(Bp + (size_t)(tn + row) * K + kk + sb, (char*)Bs + c * 16);
    }
    __syncthreads();
#pragma unroll
    for (int ks = 0; ks < 2; ks++) {
      bf16x8 af[4], bfv[4];
#pragma unroll
      for (int f = 0; f < 4; f++) {
        int rowa = wr * 64 + f * 16 + r0;
        af[f] = *(const bf16x8*)((const char*)As +
                                 ((rowa * 128 + ks * 64 + kg * 16) ^ swz128(rowa)));
        int rowb = wc * 64 + f * 16 + r0;
        bfv[f] = *(const bf16x8*)((const char*)Bs +
                                  ((rowb * 128 + ks * 64 + kg * 16) ^ swz128(rowb)));
      }
#pragma unroll
      for (int mf = 0; mf < 4; mf++)
#pragma unroll
        for (int nf = 0; nf < 4; nf++)
          acc[mf][nf] = MFMA16(af[mf], bfv[nf], acc[mf][nf]);
    }
    __syncthreads();
  }
#pragma unroll
  for (int mf = 0; mf < 4; mf++)
#pragma unroll
    for (int j = 0; j < 4; j++) {
      int row = tm + wr * 64 + mf * 16 + kg * 4 + j;
#pragma unroll
      for (int nf = 0; nf < 4; nf++) {
        int col = tn + wc * 64 + nf * 16 + r0;
        OUT[(size_t)row * 1024 + col] = acc[mf][nf][j] + bias[col];
      }
    }
}

// ---------------------------------------------------------------- flash attention pass
// T15 (QK(t) || PV(t-1)) + counted-vmcnt stage-ahead-2: K,V triple-buffered;
// body t issues stageK(t+2) + stageV(t+1) after the barrier; top-of-body wait
// is vmcnt(4) (newest K/V stages stay in flight; K(t),V(t-1) forced complete).
// No vmcnt(0) drain in the loop. Softmax in log2-domain, tree reductions,
// defer-max THR=11.5.
template<int NTH>
__device__ __forceinline__ void attn_pass32(
    const bf16* __restrict__ Kg, int kRS,
    const bf16* __restrict__ VTg, int vRS,
    int ntiles, const bf16x8* qf, bf16* Ks, bf16* Vt,  // Ks,Vt: [3][4096] bf16
    f32x16* o, float& m, float& rs) {
  const int tid = threadIdx.x;
  const int lane = tid & 63;
  const int lq = lane & 31, kg2 = lane >> 5;

  auto stageK = [&](int t) {
    bf16* kd = Ks + (t % 3) * 4096;
    const bf16* kt = Kg + (size_t)t * 64 * kRS;
#pragma unroll
    for (int i = 0; i < 512 / NTH; i++) {
      int c = i * NTH + tid;
      int r = c >> 3, kb = c & 7;
      int sb = (kb ^ ((r ^ (r >> 3)) & 7)) * 8;  // pre-swizzled source
      gl_lds16(kt + (size_t)r * kRS + sb, (char*)kd + c * 16);
    }
  };
  auto stageV = [&](int t) {
    bf16* vd = Vt + (t % 3) * 4096;
#pragma unroll
    for (int i = 0; i < 512 / NTH; i++) {
      int c = i * NTH + tid;
      int r = c >> 3, kb = c & 7;
      int sb = (kb ^ ((r ^ (r >> 3)) & 7)) * 8;
      gl_lds16(VTg + (size_t)r * vRS + t * 64 + sb, (char*)vd + c * 16);
    }
  };

  unsigned pkp[2][4][2];  // packed P of previous tile

  // QK^T + online softmax + pack -> pkp
  auto qk_softmax = [&](const char* KsC) {
    f32x16 s[2];
    s[0] = (f32x16)0.f; s[1] = (f32x16)0.f;
    __builtin_amdgcn_s_setprio(1);
#pragma unroll
    for (int kb = 0; kb < 2; kb++) {
      int row = kb * 32 + lq;
#pragma unroll
      for (int dw = 0; dw < 4; dw++) {
        bf16x8 kf = *(const bf16x8*)(KsC + ((row * 128 + dw * 32 + kg2 * 16) ^ swz128(row)));
        s[kb] = MFMA32(kf, qf[dw], s[kb]);
      }
    }
    __builtin_amdgcn_s_setprio(0);
    // tree max
    float mm[8];
#pragma unroll
    for (int j = 0; j < 8; j++)
      mm[j] = fmaxf(fmaxf(s[0][j], s[0][j + 8]), fmaxf(s[1][j], s[1][j + 8]));
    float a0 = fmaxf(mm[0], mm[1]), a1 = fmaxf(mm[2], mm[3]);
    float a2 = fmaxf(mm[4], mm[5]), a3 = fmaxf(mm[6], mm[7]);
    float vmax = fmaxf(fmaxf(a0, a1), fmaxf(a2, a3));
    vmax = fmaxf(vmax, __shfl_xor(vmax, 32, 64));
    if (__any(vmax > m + 11.5f)) {  // defer-max (log2 units)
      float mn = fmaxf(m, vmax);
      float fac = exp2_fast(m - mn);
      m = mn;
      rs *= fac;
#pragma unroll
      for (int j = 0; j < 16; j++) {
        int rowq = (j & 3) + 8 * (j >> 2) + 4 * kg2;
        float fj = __shfl(fac, rowq, 64);
        o[0][j] *= fj;
        o[1][j] *= fj;
      }
    }
    float t0 = 0.f, t1 = 0.f, t2 = 0.f, t3 = 0.f;
#pragma unroll
    for (int kb = 0; kb < 2; kb++)
#pragma unroll
      for (int j = 0; j < 16; j += 4) {
        float p0 = exp2_fast(s[kb][j + 0] - m);
        float p1 = exp2_fast(s[kb][j + 1] - m);
        float p2 = exp2_fast(s[kb][j + 2] - m);
        float p3 = exp2_fast(s[kb][j + 3] - m);
        s[kb][j + 0] = p0; s[kb][j + 1] = p1; s[kb][j + 2] = p2; s[kb][j + 3] = p3;
        t0 += p0; t1 += p1; t2 += p2; t3 += p3;
      }
    float tsum = (t0 + t1) + (t2 + t3);
    tsum += __shfl_xor(tsum, 32, 64);
    rs += tsum;
#pragma unroll
    for (int kb = 0; kb < 2; kb++)
#pragma unroll
      for (int n = 0; n < 4; n++) {
        pkp[kb][n][0] = pack2(s[kb][4 * n + 0], s[kb][4 * n + 1]);
        pkp[kb][n][1] = pack2(s[kb][4 * n + 2], s[kb][4 * n + 3]);
      }
  };

  // PV using pkp (previous tile's P) against a staged V^T buffer
  auto pv = [&](const char* VtC) {
#pragma unroll
    for (int w = 0; w < 4; w++) {
      const int kb = w >> 1, wb = w & 1;
      unsigned pushA = kg2 ? pkp[kb][2 * wb][0] : pkp[kb][2 * wb + 1][0];
      unsigned pushB = kg2 ? pkp[kb][2 * wb][1] : pkp[kb][2 * wb + 1][1];
      unsigned rcvA = __shfl_xor(pushA, 32, 64);
      unsigned rcvB = __shfl_xor(pushB, 32, 64);
      u32x4 fu;
      fu[0] = kg2 ? rcvA : pkp[kb][2 * wb][0];
      fu[1] = kg2 ? rcvB : pkp[kb][2 * wb][1];
      fu[2] = kg2 ? pkp[kb][2 * wb + 1][0] : rcvA;
      fu[3] = kg2 ? pkp[kb][2 * wb + 1][1] : rcvB;
      bf16x8 pfrag = __builtin_bit_cast(bf16x8, fu);
      __builtin_amdgcn_s_setprio(1);
#pragma unroll
      for (int db = 0; db < 2; db++) {
        int d = db * 32 + lq;
        bf16x8 vf = *(const bf16x8*)(VtC + ((d * 128 + w * 32 + kg2 * 16) ^ swz128(d)));
        o[db] = MFMA32(pfrag, vf, o[db]);
      }
      __builtin_amdgcn_s_setprio(0);
    }
  };

  // ---- prologue
  RAW_BAR();  // entry: previous pass (if any) done reading this LDS
  stageK(0); stageV(0);
  if (ntiles > 1) { stageK(1); WAITV(2); } else { WAITV(0); }
  RAW_BAR();
  qk_softmax((const char*)(Ks + 0));          // body 0 (PV deferred)
  if (ntiles > 2) stageK(2);
  if (ntiles > 1) stageV(1);

  for (int t = 1; t < ntiles; t++) {
    // newest 4 loads/thread (K(t+1),V(t)) may stay in flight; K(t),V(t-1) done
    WAITV(4);
    RAW_BAR();   // all waves past body(t-1) reads; K(t),V(t-1) visible
    if (t + 2 < ntiles) stageK(t + 2);   // writes K[(t+2)%3], read-free since BAR
    if (t + 1 < ntiles) stageV(t + 1);   // writes V[(t+1)%3], read-free since BAR
    pv((const char*)(Vt + ((t - 1) % 3) * 4096));   // consumes pkp(t-1)
    qk_softmax((const char*)(Ks + (t % 3) * 4096)); // produces pkp(t)
  }
  // epilogue: PV of last tile (V(n-1) staged at body n-2; drain everything)
  WAITV(0);
  RAW_BAR();
  pv((const char*)(Vt + ((ntiles - 1) % 3) * 4096));
}

// ---------------------------------------------------------------- merged attention
// grid = 768 blocks XCD-chunked: bid [0,512) self (bh = bid>>3, qtile = bid&7),
// bid [512,768) cross (bh = (bid-512)>>2, qtile = (bid-512)&3).
// XK[4096][3072]: cols q|k|xk0. QQK[2048][2048]: cols qq|qk.
// VTs/VT0: [bh][64][1024]; VTq: [bh][64][512]. LDS 48 KB -> 3 blocks/CU.
__global__ __launch_bounds__(256)
void k_attn(const bf16* __restrict__ XK, const bf16* __restrict__ QQK,
            const bf16* __restrict__ VTs, const bf16* __restrict__ VT0,
            const bf16* __restrict__ VTq, const float* __restrict__ gate,
            bf16* __restrict__ xat, bf16* __restrict__ qat) {
  __shared__ bf16 Ks[3 * 4096], Vt[3 * 4096];
  const int pb = blockIdx.x;
  const int bid = (pb & 7) * 96 + (pb >> 3);  // 768 = 8 x 96 chunks
  const int tid = threadIdx.x, lane = tid & 63, wv = tid >> 6;
  const int lq = lane & 31, kg2 = lane >> 5;
  constexpr float QS = 0.125f * 1.44269504088896f;  // scale * log2(e)

  if (bid < 512) {
    // ---------------- self attention
    const int bh = bid >> 3, r = bid & 7;
    const int b = bh >> 4, h = bh & 15;
    const int qtok = b * 1024 + r * 128 + wv * 32;
    bf16x8 qf[4];
#pragma unroll
    for (int dw = 0; dw < 4; dw++) {
      qf[dw] = *(const bf16x8*)(XK + (size_t)(qtok + lq) * 3072 + h * 64 + dw * 16 + kg2 * 8);
#pragma unroll
      for (int e = 0; e < 8; e++) qf[dw][e] = (bf16)((float)qf[dw][e] * QS);
    }
    f32x16 o[2];
    o[0] = (f32x16)0.f; o[1] = (f32x16)0.f;
    float m = -__builtin_inff(), rs = 0.f;
    attn_pass32<256>(XK + (size_t)(b * 1024) * 3072 + 1024 + h * 64, 3072,
                     VTs + (size_t)bh * 64 * 1024, 1024,
                     16, qf, Ks, Vt, o, m, rs);
#pragma unroll
    for (int j = 0; j < 16; j++) {
      int rowq = (j & 3) + 8 * (j >> 2) + 4 * kg2;
      float rsj = __shfl(rs, rowq, 64);
      size_t base = (size_t)(qtok + rowq) * 1024 + h * 64;
      xat[base + lq] = (bf16)(o[0][j] / rsj);
      xat[base + 32 + lq] = (bf16)(o[1][j] / rsj);
    }
  } else {
    // ---------------- cross attention
    const int c = bid - 512;
    const int bh = c >> 2, qt = c & 3;
    const int b = bh >> 4, h = bh & 15;
    const int qtok = b * 512 + qt * 128 + wv * 32;
    bf16x8 qf[4];
#pragma unroll
    for (int dw = 0; dw < 4; dw++) {
      qf[dw] = *(const bf16x8*)(QQK + (size_t)(qtok + lq) * 2048 + h * 64 + dw * 16 + kg2 * 8);
#pragma unroll
      for (int e = 0; e < 8; e++) qf[dw][e] = (bf16)((float)qf[dw][e] * QS);
    }
    const float g = tanhf(gate[h]);  // block-uniform (zero-init param -> skip seg A)
    unsigned pka[2][8] = {};         // packed g*softmax(QK0)V0 result (seg A)
    f32x16 o[2];
    o[0] = (f32x16)0.f; o[1] = (f32x16)0.f;
    float m, rs;
    if (g != 0.0f) {
      m = -__builtin_inff(); rs = 0.f;
      attn_pass32<256>(XK + (size_t)(b * 1024) * 3072 + 2048 + h * 64, 3072,
                       VT0 + (size_t)bh * 64 * 1024, 1024,
                       16, qf, Ks, Vt, o, m, rs);
#pragma unroll
      for (int j2 = 0; j2 < 8; j2++) {
        int j0 = 2 * j2;
        int rq0 = (j0 & 3) + 8 * (j0 >> 2) + 4 * kg2;  // rq1 = rq0 + 1
        float ra = __shfl(rs, rq0, 64);
        float rb = __shfl(rs, rq0 + 1, 64);
        pka[0][j2] = pack2(g * o[0][j0] / ra, g * o[0][j0 + 1] / rb);
        pka[1][j2] = pack2(g * o[1][j0] / ra, g * o[1][j0 + 1] / rb);
      }
      o[0] = (f32x16)0.f; o[1] = (f32x16)0.f;
    }
    m = -__builtin_inff(); rs = 0.f;
    attn_pass32<256>(QQK + (size_t)(b * 512) * 2048 + 1024 + h * 64, 2048,
                     VTq + (size_t)bh * 64 * 512, 512,
                     8, qf, Ks, Vt, o, m, rs);
#pragma unroll
    for (int j = 0; j < 16; j++) {
      int rowq = (j & 3) + 8 * (j >> 2) + 4 * kg2;
      float rsj = __shfl(rs, rowq, 64);
      size_t base = (size_t)(qtok + rowq) * 1024 + h * 64;
      unsigned wa = pka[0][j >> 1], wb = pka[1][j >> 1];
      unsigned short ua = (j & 1) ? (unsigned short)(wa >> 16) : (unsigned short)(wa & 0xffffu);
      unsigned short ub = (j & 1) ? (unsigned short)(wb >> 16) : (unsigned short)(wb & 0xffffu);
      float a0 = (float)__builtin_bit_cast(bf16, ua);
      float a1 = (float)__builtin_bit_cast(bf16, ub);
      qat[base + lq] = (bf16)(o[0][j] / rsj + a0);
      qat[base + 32 + lq] = (bf16)(o[1][j] / rsj + a1);
    }
  }
}

// ---------------------------------------------------------------- launch
extern "C" void kernel_launch(void* const* d_in, const int* in_sizes, int n_in,
                              void* d_out, int out_size, void* d_ws, size_t ws_size,
                              hipStream_t stream) {
  (void)in_sizes; (void)n_in; (void)out_size; (void)ws_size;
  const float* x       = (const float*)d_in[0];
  const float* query   = (const float*)d_in[1];
  const float* w_qkv   = (const float*)d_in[2];
  const float* w_kv    = (const float*)d_in[3];
  const float* w_qlin  = (const float*)d_in[4];
  const float* gate    = (const float*)d_in[5];
  const float* w_proj  = (const float*)d_in[6];
  const float* b_proj  = (const float*)d_in[7];
  const float* w_qproj = (const float*)d_in[8];
  const float* b_qproj = (const float*)d_in[9];
  float* out = (float*)d_out;

  bf16* p = (bf16*)d_ws;
  bf16* xb = p;      p += (size_t)4096 * 1024;   // 4M @ 0
  bf16* qb = p;      p += (size_t)2048 * 1024;   // 2M @ 4M
  bf16* wqkvb = p;   p += (size_t)3072 * 1024;   // 3M @ 6M (adjacent to wkvb)
  bf16* wkvb = p;    p += (size_t)2048 * 1024;   // 2M @ 9M
  bf16* wqlinb = p;  p += (size_t)3072 * 1024;   // 3M @ 11M
  bf16* wprojb = p;  p += (size_t)1024 * 1024;   // 1M @ 14M
  bf16* wqprojb = p; p += (size_t)1024 * 1024;   // 1M @ 15M
  bf16* XK = p;      p += (size_t)4096 * 3072;   // q|k|xk0 row-major
  bf16* VTs = p;     p += (size_t)64 * 64 * 1024; // self V^T
  bf16* VT0 = p;     p += (size_t)64 * 64 * 1024; // xv0 V^T
  bf16* QQK = p;     p += (size_t)2048 * 2048;   // qq|qk row-major
  bf16* VTq = p;     p += (size_t)64 * 64 * 512;  // qv V^T
  bf16* xat = p;     p += (size_t)4096 * 1024;   // (xat, qat adjacent -> proj A)
  bf16* qat = p;     p += (size_t)2048 * 1024;
  (void)wkvb;

  k_cast_all<<<2048, 256, 0, stream>>>(x, query, w_qkv, w_kv, w_qlin, w_proj, w_qproj,
                                       (bf16*)d_ws);

  // grouped big GEMM: XKV (320 blocks) + qlin (96 blocks), 8-phase schedule
  k_gemm_big<<<dim3(416), 512, 0, stream>>>(xb, qb, wqkvb, wqlinb,
                                            XK, VTs, VT0, QQK, VTq);

  k_attn<<<dim3(768), 256, 0, stream>>>(XK, QQK, VTs, VT0, VTq, gate, xat, qat);

  // fused output projections: A = [xat|qat] (6144x1024)
  k_gemm_proj<<<dim3(48 * 8), 256, 0, stream>>>(xat, wprojb, wqprojb, b_proj, b_qproj, out);
}

// Round 10
// 174.446 us; speedup vs baseline: 1.0055x; 1.0055x over previous
//
#include <hip/hip_runtime.h>

// DualAttention: B=4, N=1024, QN=512, C=1024, H=16, D=64
// bf16 MFMA everywhere, fp32 softmax (log2-domain). GEMM epilogues emit V
// pre-transposed. Big GEMMs: 256x256 tile, BK=64, 8-phase schedule, counted
// vmcnt(4). Attention: swapped QK^T, in-register softmax, T15 pipeline
// (QK(t) MFMA || PV(t-1) MFMA per iteration; P held packed in registers),
// 2-buffer K / 3-buffer V staging with per-tile drain (R8 best-known config).

using bf16 = __bf16;
typedef __bf16 bf16x4 __attribute__((ext_vector_type(4)));
typedef __bf16 bf16x8 __attribute__((ext_vector_type(8)));
typedef float  f32x4  __attribute__((ext_vector_type(4)));
typedef float  f32x16 __attribute__((ext_vector_type(16)));
typedef unsigned int u32x4 __attribute__((ext_vector_type(4)));

#define MFMA16(a, b, c) __builtin_amdgcn_mfma_f32_16x16x32_bf16((a), (b), (c), 0, 0, 0)
#define MFMA32(a, b, c) __builtin_amdgcn_mfma_f32_32x32x16_bf16((a), (b), (c), 0, 0, 0)

// XOR swizzle for 128B LDS rows (8 granules of 16B).
__device__ __forceinline__ int swz128(int row) { return ((row ^ (row >> 3)) & 7) << 4; }

__device__ __forceinline__ void gl_lds16(const void* g, void* l) {
  __builtin_amdgcn_global_load_lds(
      (const __attribute__((address_space(1))) unsigned int*)g,
      (__attribute__((address_space(3))) unsigned int*)l, 16, 0, 0);
}

__device__ __forceinline__ unsigned pack2(float a, float b) {
  unsigned short ua = __builtin_bit_cast(unsigned short, (bf16)a);
  unsigned short ub = __builtin_bit_cast(unsigned short, (bf16)b);
  return (unsigned)ua | ((unsigned)ub << 16);
}

__device__ __forceinline__ float exp2_fast(float x) {  // v_exp_f32 IS 2^x
  float r;
  asm("v_exp_f32 %0, %1" : "=v"(r) : "v"(x));
  return r;
}

#define WAITV(N) asm volatile("s_waitcnt vmcnt(" #N ")" ::: "memory")
#define LGKM0()  asm volatile("s_waitcnt lgkmcnt(0)" ::: "memory")
#define SCHED0() __builtin_amdgcn_sched_barrier(0)
#define RAW_BAR() do { __builtin_amdgcn_s_barrier(); asm volatile("" ::: "memory"); } while (0)

// ---------------------------------------------------------------- fused cast fp32->bf16
// ws layout (elements, M = 1<<20): xb@0(4M) qb@4M(2M) wqkv@6M(3M) wkv@9M(2M)
// wqlin@11M(3M) wproj@14M(1M) wqproj@15M(1M). Must match kernel_launch.
__global__ void k_cast_all(const float* __restrict__ s0, const float* __restrict__ s1,
                           const float* __restrict__ s2, const float* __restrict__ s3,
                           const float* __restrict__ s4, const float* __restrict__ s5,
                           const float* __restrict__ s6, bf16* __restrict__ dst) {
  constexpr size_t MM = 1u << 20;
  constexpr size_t o1 = 4 * MM, o2 = 6 * MM, o3 = 9 * MM, o4 = 11 * MM,
                   o5 = 14 * MM, o6 = 15 * MM, total = 16 * MM;
  size_t stride = (size_t)gridDim.x * blockDim.x * 8;
  for (size_t i = ((size_t)blockIdx.x * blockDim.x + threadIdx.x) * 8; i < total; i += stride) {
    const float* s; size_t loc;
    if (i < o1)      { s = s0; loc = i; }
    else if (i < o2) { s = s1; loc = i - o1; }
    else if (i < o3) { s = s2; loc = i - o2; }
    else if (i < o4) { s = s3; loc = i - o3; }
    else if (i < o5) { s = s4; loc = i - o4; }
    else if (i < o6) { s = s5; loc = i - o5; }
    else             { s = s6; loc = i - o6; }
    float4 a = *(const float4*)(s + loc);
    float4 b = *(const float4*)(s + loc + 4);
    bf16x8 o;
    o[0] = (bf16)a.x; o[1] = (bf16)a.y; o[2] = (bf16)a.z; o[3] = (bf16)a.w;
    o[4] = (bf16)b.x; o[5] = (bf16)b.y; o[6] = (bf16)b.z; o[7] = (bf16)b.w;
    *(bf16x8*)(dst + i) = o;
  }
}

// ---------------------------------------------------------------- big grouped GEMM (8-phase)
// 256x256 tile, BK=64 (2 k-halves of 32), 512 threads (8 waves 2Mx4N).
// LDS: A,B each [2 buf][2 kh][256 rows][32 k] bf16 = 64 KB -> 128 KB total.
// Per tile j: 4 phases; each {ds_read frags | stage half-tile} -> barrier ->
// lgkmcnt(0) -> 16 MFMA -> barrier. Boundary: vmcnt(4).
// Groups: bid [0,320): XKV (xb x [wqkv|wkv], M=4096 N=5120);
//         bid [320,416): qlin (qb x wqlin, M=2048 N=3072).
__global__ __launch_bounds__(512)
void k_gemm_big(const bf16* __restrict__ xb, const bf16* __restrict__ qb,
                const bf16* __restrict__ wqkvb, const bf16* __restrict__ wqlinb,
                bf16* __restrict__ XK, bf16* __restrict__ VTs, bf16* __restrict__ VT0,
                bf16* __restrict__ QQK, bf16* __restrict__ VTq) {
  constexpr int K = 1024, NT = 16;
  __shared__ bf16 As[2 * 2 * 256 * 32];
  __shared__ bf16 Bs[2 * 2 * 256 * 32];
  const int tid = threadIdx.x;
  const int lane = tid & 63, w = tid >> 6;
  const int wm = w >> 2, wn = w & 3;
  const int r0 = lane & 15, kg = lane >> 4;
  const int bid = ((int)blockIdx.x & 7) * 52 + ((int)blockIdx.x >> 3);  // 416 = 8*52
  int grp, tm, tn;
  const bf16 *Ap, *Bp;
  if (bid < 320) { grp = 0; tm = (bid / 20) * 256; tn = (bid % 20) * 256; Ap = xb; Bp = wqkvb; }
  else { grp = 1; int t = bid - 320; tm = (t / 12) * 256; tn = (t % 12) * 256; Ap = qb; Bp = wqlinb; }

  auto stage = [&](int T, int mat, int kh) {
    const bf16* src = mat ? Bp : Ap;
    const int t0 = mat ? tn : tm;
    char* base = (char*)(mat ? (void*)Bs : (void*)As) + (((T & 1) * 2 + kh) << 14);
#pragma unroll
    for (int i = 0; i < 2; i++) {
      int c = i * 512 + tid;
      int row = c >> 2, g = c & 3;
      int sg = (g ^ ((row >> 1) & 3)) * 8;  // pre-swizzled source granule
      gl_lds16(src + (size_t)(t0 + row) * K + T * 64 + kh * 32 + sg, base + c * 16);
    }
  };
  auto ldA = [&](int bi, int kh, int row) -> bf16x8 {
    return *(const bf16x8*)((const char*)As + ((bi * 2 + kh) << 14) + row * 64 +
                            ((kg ^ ((row >> 1) & 3)) << 4));
  };
  auto ldB = [&](int bi, int kh, int row) -> bf16x8 {
    return *(const bf16x8*)((const char*)Bs + ((bi * 2 + kh) << 14) + row * 64 +
                            ((kg ^ ((row >> 1) & 3)) << 4));
  };

  f32x4 acc[8][4] = {};

  stage(0, 0, 0); stage(0, 1, 0); stage(0, 0, 1); stage(0, 1, 1);
  stage(1, 0, 0); stage(1, 1, 0);
  WAITV(4);
  RAW_BAR();

  for (int j = 0; j < NT; ++j) {
    const int bi = j & 1;
    bf16x8 af[4], bfk[4];
    // ---- phase 1: (mh0, kh0)
#pragma unroll
    for (int i = 0; i < 4; i++) af[i] = ldA(bi, 0, wm * 128 + i * 16 + r0);
#pragma unroll
    for (int nf = 0; nf < 4; nf++) bfk[nf] = ldB(bi, 0, wn * 64 + nf * 16 + r0);
    if (j + 1 < NT) stage(j + 1, 0, 1);
    RAW_BAR(); LGKM0(); SCHED0();
    __builtin_amdgcn_s_setprio(1);
#pragma unroll
    for (int i = 0; i < 4; i++)
#pragma unroll
      for (int nf = 0; nf < 4; nf++) acc[i][nf] = MFMA16(af[i], bfk[nf], acc[i][nf]);
    __builtin_amdgcn_s_setprio(0);
    RAW_BAR();
    // ---- phase 2: (mh1, kh0)
#pragma unroll
    for (int i = 0; i < 4; i++) af[i] = ldA(bi, 0, wm * 128 + 64 + i * 16 + r0);
    if (j + 1 < NT) stage(j + 1, 1, 1);
    RAW_BAR(); LGKM0(); SCHED0();
    __builtin_amdgcn_s_setprio(1);
#pragma unroll
    for (int i = 0; i < 4; i++)
#pragma unroll
      for (int nf = 0; nf < 4; nf++) acc[4 + i][nf] = MFMA16(af[i], bfk[nf], acc[4 + i][nf]);
    __builtin_amdgcn_s_setprio(0);
    RAW_BAR();
    // ---- phase 3: (mh0, kh1)
#pragma unroll
    for (int i = 0; i < 4; i++) af[i] = ldA(bi, 1, wm * 128 + i * 16 + r0);
#pragma unroll
    for (int nf = 0; nf < 4; nf++) bfk[nf] = ldB(bi, 1, wn * 64 + nf * 16 + r0);
    if (j + 2 < NT) stage(j + 2, 0, 0);
    RAW_BAR(); LGKM0(); SCHED0();
    __builtin_amdgcn_s_setprio(1);
#pragma unroll
    for (int i = 0; i < 4; i++)
#pragma unroll
      for (int nf = 0; nf < 4; nf++) acc[i][nf] = MFMA16(af[i], bfk[nf], acc[i][nf]);
    __builtin_amdgcn_s_setprio(0);
    RAW_BAR();
    // ---- phase 4: (mh1, kh1)
#pragma unroll
    for (int i = 0; i < 4; i++) af[i] = ldA(bi, 1, wm * 128 + 64 + i * 16 + r0);
    if (j + 2 < NT) stage(j + 2, 1, 0);
    RAW_BAR(); LGKM0(); SCHED0();
    __builtin_amdgcn_s_setprio(1);
#pragma unroll
    for (int i = 0; i < 4; i++)
#pragma unroll
      for (int nf = 0; nf < 4; nf++) acc[4 + i][nf] = MFMA16(af[i], bfk[nf], acc[4 + i][nf]);
    __builtin_amdgcn_s_setprio(0);
    if (j < NT - 2) { WAITV(4); } else { WAITV(0); }
    RAW_BAR();
  }

  // ---------------- epilogue (tn/tm uniform per block; ranges never straddle)
#pragma unroll
  for (int mf = 0; mf < 8; mf++) {
    const int rowb = tm + wm * 128 + mf * 16 + kg * 4;  // 4 consecutive rows (j)
#pragma unroll
    for (int nf = 0; nf < 4; nf++) {
      const int coln = tn + wn * 64 + nf * 16 + r0;
      bool rm; int rmcol = coln, vbase = 0, tokb = 10, rs_ = 3072;
      bf16* vt = VTs;
      bf16* rmp = XK;
      if (grp == 0) {
        if (tn < 2048)      { rm = true; }
        else if (tn < 3072) { rm = false; vbase = 2048; vt = VTs; }
        else if (tn < 4096) { rm = true; rmcol = coln - 1024; }
        else                { rm = false; vbase = 4096; vt = VT0; }
      } else {
        rs_ = 2048; tokb = 9; rmp = QQK;
        if (tn < 2048) { rm = true; }
        else           { rm = false; vbase = 2048; vt = VTq; }
      }
      if (rm) {
#pragma unroll
        for (int j = 0; j < 4; j++)
          rmp[(size_t)(rowb + j) * rs_ + rmcol] = (bf16)acc[mf][nf][j];
      } else {
        int dg = coln - vbase, h_ = dg >> 6, dd = dg & 63;
        int bq = rowb >> tokb, tok = rowb & ((1 << tokb) - 1);
        bf16x4 wv;
#pragma unroll
        for (int j = 0; j < 4; j++) wv[j] = (bf16)acc[mf][nf][j];
        *(bf16x4*)(vt + (((size_t)((bq * 16 + h_) * 64 + dd)) << tokb) + tok) = wv;
      }
    }
  }
}

// ---------------------------------------------------------------- proj GEMM (128x128, proven)
// C[6144,1024] = [xat|qat] x [w_proj|w_qproj]^T + bias, fp32 out to d_out.
__global__ __launch_bounds__(256)
void k_gemm_proj(const bf16* __restrict__ A, const bf16* __restrict__ B0,
                 const bf16* __restrict__ B1, const float* __restrict__ bias0,
                 const float* __restrict__ bias1, float* __restrict__ OUT) {
  constexpr int K = 1024, N = 1024;
  __shared__ bf16 As[128 * 64];
  __shared__ bf16 Bs[128 * 64];
  const int tid = threadIdx.x;
  const int lane = tid & 63, w = tid >> 6;
  const int wr = w >> 1, wc = w & 1;
  const int nbx = N / 128;
  const int bid = ((int)blockIdx.x & 7) * ((int)gridDim.x >> 3) + ((int)blockIdx.x >> 3);
  const int tm = (bid / nbx) * 128, tn = (bid % nbx) * 128;
  const int r0 = lane & 15, kg = lane >> 4;
  const bf16* Bp = (tm < 4096) ? B0 : B1;
  const float* bias = (tm < 4096) ? bias0 : bias1;
  f32x4 acc[4][4] = {};
  for (int kk = 0; kk < K; kk += 64) {
#pragma unroll
    for (int i = 0; i < 4; i++) {
      int c = i * 256 + tid;
      int row = c >> 3, kb = c & 7;
      int sb = (kb ^ ((row ^ (row >> 3)) & 7)) * 8;
      gl_lds16(A + (size_t)(tm + row) * K + kk + sb, (char*)As + c * 16);
      gl_lds16(Bp + (size_t)(tn + row) * K + kk + sb, (char*)Bs + c * 16);
    }
    __syncthreads();
#pragma unroll
    for (int ks = 0; ks < 2; ks++) {
      bf16x8 af[4], bfv[4];
#pragma unroll
      for (int f = 0; f < 4; f++) {
        int rowa = wr * 64 + f * 16 + r0;
        af[f] = *(const bf16x8*)((const char*)As +
                                 ((rowa * 128 + ks * 64 + kg * 16) ^ swz128(rowa)));
        int rowb = wc * 64 + f * 16 + r0;
        bfv[f] = *(const bf16x8*)((const char*)Bs +
                                  ((rowb * 128 + ks * 64 + kg * 16) ^ swz128(rowb)));
      }
#pragma unroll
      for (int mf = 0; mf < 4; mf++)
#pragma unroll
        for (int nf = 0; nf < 4; nf++)
          acc[mf][nf] = MFMA16(af[mf], bfv[nf], acc[mf][nf]);
    }
    __syncthreads();
  }
#pragma unroll
  for (int mf = 0; mf < 4; mf++)
#pragma unroll
    for (int j = 0; j < 4; j++) {
      int row = tm + wr * 64 + mf * 16 + kg * 4 + j;
#pragma unroll
      for (int nf = 0; nf < 4; nf++) {
        int col = tn + wc * 64 + nf * 16 + r0;
        OUT[(size_t)row * 1024 + col] = acc[mf][nf][j] + bias[col];
      }
    }
}

// ---------------------------------------------------------------- flash attention pass (T15)
// Iteration t computes QK^T(t) and PV(t-1) as independent MFMA streams; P(t)
// is packed into registers (pkp) and consumed next iteration. K double-buffer,
// V TRIPLE-buffer (PV lags one tile). One barrier/tile. Online softmax in
// log2-domain, tree reductions, defer-max THR=11.5.
template<int NTH>
__device__ __forceinline__ void attn_pass32(
    const bf16* __restrict__ Kg, int kRS,
    const bf16* __restrict__ VTg, int vRS,
    int ntiles, const bf16x8* qf, bf16* Ks, bf16* Vt,  // Ks:[2][4096], Vt:[3][4096]
    f32x16* o, float& m, float& rs) {
  const int tid = threadIdx.x;
  const int lane = tid & 63;
  const int lq = lane & 31, kg2 = lane >> 5;

  auto stageKV = [&](int t) {
    bf16* kd = Ks + (t & 1) * 4096;
    bf16* vd = Vt + (t % 3) * 4096;
    const bf16* kt = Kg + (size_t)t * 64 * kRS;
#pragma unroll
    for (int i = 0; i < 512 / NTH; i++) {
      int c = i * NTH + tid;
      int r = c >> 3, kb = c & 7;
      int sb = (kb ^ ((r ^ (r >> 3)) & 7)) * 8;  // pre-swizzled source
      gl_lds16(kt + (size_t)r * kRS + sb, (char*)kd + c * 16);
    }
#pragma unroll
    for (int i = 0; i < 512 / NTH; i++) {
      int c = i * NTH + tid;
      int r = c >> 3, kb = c & 7;
      int sb = (kb ^ ((r ^ (r >> 3)) & 7)) * 8;
      gl_lds16(VTg + (size_t)r * vRS + t * 64 + sb, (char*)vd + c * 16);
    }
  };

  unsigned pkp[2][4][2];  // packed P of previous tile

  // QK^T + online softmax + pack -> pkp (pure function of staged K buffer)
  auto qk_softmax = [&](const char* KsC) {
    f32x16 s[2];
    s[0] = (f32x16)0.f; s[1] = (f32x16)0.f;
    __builtin_amdgcn_s_setprio(1);
#pragma unroll
    for (int kb = 0; kb < 2; kb++) {
      int row = kb * 32 + lq;
#pragma unroll
      for (int dw = 0; dw < 4; dw++) {
        bf16x8 kf = *(const bf16x8*)(KsC + ((row * 128 + dw * 32 + kg2 * 16) ^ swz128(row)));
        s[kb] = MFMA32(kf, qf[dw], s[kb]);
      }
    }
    __builtin_amdgcn_s_setprio(0);
    // tree max
    float mm[8];
#pragma unroll
    for (int j = 0; j < 8; j++)
      mm[j] = fmaxf(fmaxf(s[0][j], s[0][j + 8]), fmaxf(s[1][j], s[1][j + 8]));
    float a0 = fmaxf(mm[0], mm[1]), a1 = fmaxf(mm[2], mm[3]);
    float a2 = fmaxf(mm[4], mm[5]), a3 = fmaxf(mm[6], mm[7]);
    float vmax = fmaxf(fmaxf(a0, a1), fmaxf(a2, a3));
    vmax = fmaxf(vmax, __shfl_xor(vmax, 32, 64));
    if (__any(vmax > m + 11.5f)) {  // defer-max (log2 units)
      float mn = fmaxf(m, vmax);
      float fac = exp2_fast(m - mn);
      m = mn;
      rs *= fac;
#pragma unroll
      for (int j = 0; j < 16; j++) {
        int rowq = (j & 3) + 8 * (j >> 2) + 4 * kg2;
        float fj = __shfl(fac, rowq, 64);
        o[0][j] *= fj;
        o[1][j] *= fj;
      }
    }
    float t0 = 0.f, t1 = 0.f, t2 = 0.f, t3 = 0.f;
#pragma unroll
    for (int kb = 0; kb < 2; kb++)
#pragma unroll
      for (int j = 0; j < 16; j += 4) {
        float p0 = exp2_fast(s[kb][j + 0] - m);
        float p1 = exp2_fast(s[kb][j + 1] - m);
        float p2 = exp2_fast(s[kb][j + 2] - m);
        float p3 = exp2_fast(s[kb][j + 3] - m);
        s[kb][j + 0] = p0; s[kb][j + 1] = p1; s[kb][j + 2] = p2; s[kb][j + 3] = p3;
        t0 += p0; t1 += p1; t2 += p2; t3 += p3;
      }
    float tsum = (t0 + t1) + (t2 + t3);
    tsum += __shfl_xor(tsum, 32, 64);
    rs += tsum;
#pragma unroll
    for (int kb = 0; kb < 2; kb++)
#pragma unroll
      for (int n = 0; n < 4; n++) {
        pkp[kb][n][0] = pack2(s[kb][4 * n + 0], s[kb][4 * n + 1]);
        pkp[kb][n][1] = pack2(s[kb][4 * n + 2], s[kb][4 * n + 3]);
      }
  };

  // PV using pkp (previous tile's P) against a staged V^T buffer
  auto pv = [&](const char* VtC) {
#pragma unroll
    for (int w = 0; w < 4; w++) {
      const int kb = w >> 1, wb = w & 1;
      unsigned pushA = kg2 ? pkp[kb][2 * wb][0] : pkp[kb][2 * wb + 1][0];
      unsigned pushB = kg2 ? pkp[kb][2 * wb][1] : pkp[kb][2 * wb + 1][1];
      unsigned rcvA = __shfl_xor(pushA, 32, 64);
      unsigned rcvB = __shfl_xor(pushB, 32, 64);
      u32x4 fu;
      fu[0] = kg2 ? rcvA : pkp[kb][2 * wb][0];
      fu[1] = kg2 ? rcvB : pkp[kb][2 * wb][1];
      fu[2] = kg2 ? pkp[kb][2 * wb + 1][0] : rcvA;
      fu[3] = kg2 ? pkp[kb][2 * wb + 1][1] : rcvB;
      bf16x8 pfrag = __builtin_bit_cast(bf16x8, fu);
      __builtin_amdgcn_s_setprio(1);
#pragma unroll
      for (int db = 0; db < 2; db++) {
        int d = db * 32 + lq;
        bf16x8 vf = *(const bf16x8*)(VtC + ((d * 128 + w * 32 + kg2 * 16) ^ swz128(d)));
        o[db] = MFMA32(pfrag, vf, o[db]);
      }
      __builtin_amdgcn_s_setprio(0);
    }
  };

  RAW_BAR();  // entry: previous pass (if any) done reading this LDS
  stageKV(0);
  if (ntiles > 1) { stageKV(1); WAITV(4); } else { WAITV(0); }
  RAW_BAR();
  // tile 0: QK + softmax only (PV deferred)
  qk_softmax((const char*)(Ks + 0));

  for (int t = 1; t < ntiles; t++) {
    WAITV(0);   // stage(t) (issued last iteration) fully landed
    RAW_BAR();  // ...visible to all waves; all waves done with body(t-1) reads
    if (t + 1 < ntiles) stageKV(t + 1);  // overwrites Ks[(t-1)&1], Vt[(t+1)%3] (free)
    // body: QK(t) and PV(t-1) are independent MFMA streams (scheduler interleaves);
    // softmax(t) overlaps PV's shadow; rescale (rare) depends on o after PV lands.
    const char* KsC = (const char*)(Ks + (t & 1) * 4096);
    const char* VtP = (const char*)(Vt + ((t - 1) % 3) * 4096);
    pv(VtP);           // consumes pkp(t-1)
    qk_softmax(KsC);   // produces pkp(t); s-dep places it after QK MFMAs
  }
  // epilogue: PV of last tile
  pv((const char*)(Vt + ((ntiles - 1) % 3) * 4096));
}

// ---------------------------------------------------------------- merged attention
// grid = 768 blocks XCD-chunked: bid [0,512) self (bh = bid>>3, qtile = bid&7),
// bid [512,768) cross (bh = (bid-512)>>2, qtile = (bid-512)&3).
// XK[4096][3072]: cols q|k|xk0. QQK[2048][2048]: cols qq|qk.
// VTs/VT0: [bh][64][1024]; VTq: [bh][64][512].
__global__ __launch_bounds__(256)
void k_attn(const bf16* __restrict__ XK, const bf16* __restrict__ QQK,
            const bf16* __restrict__ VTs, const bf16* __restrict__ VT0,
            const bf16* __restrict__ VTq, const float* __restrict__ gate,
            bf16* __restrict__ xat, bf16* __restrict__ qat) {
  __shared__ bf16 Ks[2 * 4096], Vt[3 * 4096];
  const int pb = blockIdx.x;
  const int bid = (pb & 7) * 96 + (pb >> 3);  // 768 = 8 x 96 chunks
  const int tid = threadIdx.x, lane = tid & 63, wv = tid >> 6;
  const int lq = lane & 31, kg2 = lane >> 5;
  constexpr float QS = 0.125f * 1.44269504088896f;  // scale * log2(e)

  if (bid < 512) {
    // ---------------- self attention
    const int bh = bid >> 3, r = bid & 7;
    const int b = bh >> 4, h = bh & 15;
    const int qtok = b * 1024 + r * 128 + wv * 32;
    bf16x8 qf[4];
#pragma unroll
    for (int dw = 0; dw < 4; dw++) {
      qf[dw] = *(const bf16x8*)(XK + (size_t)(qtok + lq) * 3072 + h * 64 + dw * 16 + kg2 * 8);
#pragma unroll
      for (int e = 0; e < 8; e++) qf[dw][e] = (bf16)((float)qf[dw][e] * QS);
    }
    f32x16 o[2];
    o[0] = (f32x16)0.f; o[1] = (f32x16)0.f;
    float m = -__builtin_inff(), rs = 0.f;
    attn_pass32<256>(XK + (size_t)(b * 1024) * 3072 + 1024 + h * 64, 3072,
                     VTs + (size_t)bh * 64 * 1024, 1024,
                     16, qf, Ks, Vt, o, m, rs);
#pragma unroll
    for (int j = 0; j < 16; j++) {
      int rowq = (j & 3) + 8 * (j >> 2) + 4 * kg2;
      float rsj = __shfl(rs, rowq, 64);
      size_t base = (size_t)(qtok + rowq) * 1024 + h * 64;
      xat[base + lq] = (bf16)(o[0][j] / rsj);
      xat[base + 32 + lq] = (bf16)(o[1][j] / rsj);
    }
  } else {
    // ---------------- cross attention
    const int c = bid - 512;
    const int bh = c >> 2, qt = c & 3;
    const int b = bh >> 4, h = bh & 15;
    const int qtok = b * 512 + qt * 128 + wv * 32;
    bf16x8 qf[4];
#pragma unroll
    for (int dw = 0; dw < 4; dw++) {
      qf[dw] = *(const bf16x8*)(QQK + (size_t)(qtok + lq) * 2048 + h * 64 + dw * 16 + kg2 * 8);
#pragma unroll
      for (int e = 0; e < 8; e++) qf[dw][e] = (bf16)((float)qf[dw][e] * QS);
    }
    const float g = tanhf(gate[h]);  // block-uniform (zero-init param -> skip seg A)
    unsigned pka[2][8] = {};         // packed g*softmax(QK0)V0 result (seg A)
    f32x16 o[2];
    o[0] = (f32x16)0.f; o[1] = (f32x16)0.f;
    float m, rs;
    if (g != 0.0f) {
      m = -__builtin_inff(); rs = 0.f;
      attn_pass32<256>(XK + (size_t)(b * 1024) * 3072 + 2048 + h * 64, 3072,
                       VT0 + (size_t)bh * 64 * 1024, 1024,
                       16, qf, Ks, Vt, o, m, rs);
#pragma unroll
      for (int j2 = 0; j2 < 8; j2++) {
        int j0 = 2 * j2;
        int rq0 = (j0 & 3) + 8 * (j0 >> 2) + 4 * kg2;  // rq1 = rq0 + 1
        float ra = __shfl(rs, rq0, 64);
        float rb = __shfl(rs, rq0 + 1, 64);
        pka[0][j2] = pack2(g * o[0][j0] / ra, g * o[0][j0 + 1] / rb);
        pka[1][j2] = pack2(g * o[1][j0] / ra, g * o[1][j0 + 1] / rb);
      }
      o[0] = (f32x16)0.f; o[1] = (f32x16)0.f;
    }
    m = -__builtin_inff(); rs = 0.f;
    attn_pass32<256>(QQK + (size_t)(b * 512) * 2048 + 1024 + h * 64, 2048,
                     VTq + (size_t)bh * 64 * 512, 512,
                     8, qf, Ks, Vt, o, m, rs);
#pragma unroll
    for (int j = 0; j < 16; j++) {
      int rowq = (j & 3) + 8 * (j >> 2) + 4 * kg2;
      float rsj = __shfl(rs, rowq, 64);
      size_t base = (size_t)(qtok + rowq) * 1024 + h * 64;
      unsigned wa = pka[0][j >> 1], wb = pka[1][j >> 1];
      unsigned short ua = (j & 1) ? (unsigned short)(wa >> 16) : (unsigned short)(wa & 0xffffu);
      unsigned short ub = (j & 1) ? (unsigned short)(wb >> 16) : (unsigned short)(wb & 0xffffu);
      float a0 = (float)__builtin_bit_cast(bf16, ua);
      float a1 = (float)__builtin_bit_cast(bf16, ub);
      qat[base + lq] = (bf16)(o[0][j] / rsj + a0);
      qat[base + 32 + lq] = (bf16)(o[1][j] / rsj + a1);
    }
  }
}

// ---------------------------------------------------------------- launch
extern "C" void kernel_launch(void* const* d_in, const int* in_sizes, int n_in,
                              void* d_out, int out_size, void* d_ws, size_t ws_size,
                              hipStream_t stream) {
  (void)in_sizes; (void)n_in; (void)out_size; (void)ws_size;
  const float* x       = (const float*)d_in[0];
  const float* query   = (const float*)d_in[1];
  const float* w_qkv   = (const float*)d_in[2];
  const float* w_kv    = (const float*)d_in[3];
  const float* w_qlin  = (const float*)d_in[4];
  const float* gate    = (const float*)d_in[5];
  const float* w_proj  = (const float*)d_in[6];
  const float* b_proj  = (const float*)d_in[7];
  const float* w_qproj = (const float*)d_in[8];
  const float* b_qproj = (const float*)d_in[9];
  float* out = (float*)d_out;

  bf16* p = (bf16*)d_ws;
  bf16* xb = p;      p += (size_t)4096 * 1024;   // 4M @ 0
  bf16* qb = p;      p += (size_t)2048 * 1024;   // 2M @ 4M
  bf16* wqkvb = p;   p += (size_t)3072 * 1024;   // 3M @ 6M (adjacent to wkvb)
  bf16* wkvb = p;    p += (size_t)2048 * 1024;   // 2M @ 9M
  bf16* wqlinb = p;  p += (size_t)3072 * 1024;   // 3M @ 11M
  bf16* wprojb = p;  p += (size_t)1024 * 1024;   // 1M @ 14M
  bf16* wqprojb = p; p += (size_t)1024 * 1024;   // 1M @ 15M
  bf16* XK = p;      p += (size_t)4096 * 3072;   // q|k|xk0 row-major
  bf16* VTs = p;     p += (size_t)64 * 64 * 1024; // self V^T
  bf16* VT0 = p;     p += (size_t)64 * 64 * 1024; // xv0 V^T
  bf16* QQK = p;     p += (size_t)2048 * 2048;   // qq|qk row-major
  bf16* VTq = p;     p += (size_t)64 * 64 * 512;  // qv V^T
  bf16* xat = p;     p += (size_t)4096 * 1024;   // (xat, qat adjacent -> proj A)
  bf16* qat = p;     p += (size_t)2048 * 1024;
  (void)wkvb;

  k_cast_all<<<2048, 256, 0, stream>>>(x, query, w_qkv, w_kv, w_qlin, w_proj, w_qproj,
                                       (bf16*)d_ws);

  // grouped big GEMM: XKV (320 blocks) + qlin (96 blocks), 8-phase schedule
  k_gemm_big<<<dim3(416), 512, 0, stream>>>(xb, qb, wqkvb, wqlinb,
                                            XK, VTs, VT0, QQK, VTq);

  k_attn<<<dim3(768), 256, 0, stream>>>(XK, QQK, VTs, VT0, VTq, gate, xat, qat);

  // fused output projections: A = [xat|qat] (6144x1024)
  k_gemm_proj<<<dim3(48 * 8), 256, 0, stream>>>(xat, wprojb, wqprojb, b_proj, b_qproj, out);
}

// Round 11
// 162.654 us; speedup vs baseline: 1.0784x; 1.0725x over previous
//
#include <hip/hip_runtime.h>

// DualAttention: B=4, N=1024, QN=512, C=1024, H=16, D=64
// bf16 MFMA everywhere, fp32 softmax (log2-domain). GEMM epilogues emit V
// pre-transposed. Big GEMMs: 256x256 tile, BK=64, 8-phase schedule, counted
// vmcnt(4). Attention: swapped QK^T, in-register softmax, T15 pipeline,
// R8 staging config, XCD-proportional self/cross block mapping (load balance).

using bf16 = __bf16;
typedef __bf16 bf16x4 __attribute__((ext_vector_type(4)));
typedef __bf16 bf16x8 __attribute__((ext_vector_type(8)));
typedef float  f32x4  __attribute__((ext_vector_type(4)));
typedef float  f32x16 __attribute__((ext_vector_type(16)));
typedef unsigned int u32x4 __attribute__((ext_vector_type(4)));

#define MFMA16(a, b, c) __builtin_amdgcn_mfma_f32_16x16x32_bf16((a), (b), (c), 0, 0, 0)
#define MFMA32(a, b, c) __builtin_amdgcn_mfma_f32_32x32x16_bf16((a), (b), (c), 0, 0, 0)

// XOR swizzle for 128B LDS rows (8 granules of 16B).
__device__ __forceinline__ int swz128(int row) { return ((row ^ (row >> 3)) & 7) << 4; }

__device__ __forceinline__ void gl_lds16(const void* g, void* l) {
  __builtin_amdgcn_global_load_lds(
      (const __attribute__((address_space(1))) unsigned int*)g,
      (__attribute__((address_space(3))) unsigned int*)l, 16, 0, 0);
}

__device__ __forceinline__ unsigned pack2(float a, float b) {
  unsigned short ua = __builtin_bit_cast(unsigned short, (bf16)a);
  unsigned short ub = __builtin_bit_cast(unsigned short, (bf16)b);
  return (unsigned)ua | ((unsigned)ub << 16);
}

__device__ __forceinline__ float exp2_fast(float x) {  // v_exp_f32 IS 2^x
  float r;
  asm("v_exp_f32 %0, %1" : "=v"(r) : "v"(x));
  return r;
}

#define WAITV(N) asm volatile("s_waitcnt vmcnt(" #N ")" ::: "memory")
#define LGKM0()  asm volatile("s_waitcnt lgkmcnt(0)" ::: "memory")
#define SCHED0() __builtin_amdgcn_sched_barrier(0)
#define RAW_BAR() do { __builtin_amdgcn_s_barrier(); asm volatile("" ::: "memory"); } while (0)

// ---------------------------------------------------------------- fused cast fp32->bf16
// ws layout (elements, M = 1<<20): xb@0(4M) qb@4M(2M) wqkv@6M(3M) wkv@9M(2M)
// wqlin@11M(3M) wproj@14M(1M) wqproj@15M(1M). Must match kernel_launch.
__global__ void k_cast_all(const float* __restrict__ s0, const float* __restrict__ s1,
                           const float* __restrict__ s2, const float* __restrict__ s3,
                           const float* __restrict__ s4, const float* __restrict__ s5,
                           const float* __restrict__ s6, bf16* __restrict__ dst) {
  constexpr size_t MM = 1u << 20;
  constexpr size_t o1 = 4 * MM, o2 = 6 * MM, o3 = 9 * MM, o4 = 11 * MM,
                   o5 = 14 * MM, o6 = 15 * MM, total = 16 * MM;
  size_t stride = (size_t)gridDim.x * blockDim.x * 8;
  for (size_t i = ((size_t)blockIdx.x * blockDim.x + threadIdx.x) * 8; i < total; i += stride) {
    const float* s; size_t loc;
    if (i < o1)      { s = s0; loc = i; }
    else if (i < o2) { s = s1; loc = i - o1; }
    else if (i < o3) { s = s2; loc = i - o2; }
    else if (i < o4) { s = s3; loc = i - o3; }
    else if (i < o5) { s = s4; loc = i - o4; }
    else if (i < o6) { s = s5; loc = i - o5; }
    else             { s = s6; loc = i - o6; }
    float4 a = *(const float4*)(s + loc);
    float4 b = *(const float4*)(s + loc + 4);
    bf16x8 o;
    o[0] = (bf16)a.x; o[1] = (bf16)a.y; o[2] = (bf16)a.z; o[3] = (bf16)a.w;
    o[4] = (bf16)b.x; o[5] = (bf16)b.y; o[6] = (bf16)b.z; o[7] = (bf16)b.w;
    *(bf16x8*)(dst + i) = o;
  }
}

// ---------------------------------------------------------------- big grouped GEMM (8-phase)
// 256x256 tile, BK=64 (2 k-halves of 32), 512 threads (8 waves 2Mx4N).
// LDS: A,B each [2 buf][2 kh][256 rows][32 k] bf16 = 64 KB -> 128 KB total.
// Per tile j: 4 phases; each {ds_read frags | stage half-tile} -> barrier ->
// lgkmcnt(0) -> 16 MFMA -> barrier. Boundary: vmcnt(4).
// Groups: bid [0,320): XKV (xb x [wqkv|wkv], M=4096 N=5120);
//         bid [320,416): qlin (qb x wqlin, M=2048 N=3072).
__global__ __launch_bounds__(512)
void k_gemm_big(const bf16* __restrict__ xb, const bf16* __restrict__ qb,
                const bf16* __restrict__ wqkvb, const bf16* __restrict__ wqlinb,
                bf16* __restrict__ XK, bf16* __restrict__ VTs, bf16* __restrict__ VT0,
                bf16* __restrict__ QQK, bf16* __restrict__ VTq) {
  constexpr int K = 1024, NT = 16;
  __shared__ bf16 As[2 * 2 * 256 * 32];
  __shared__ bf16 Bs[2 * 2 * 256 * 32];
  const int tid = threadIdx.x;
  const int lane = tid & 63, w = tid >> 6;
  const int wm = w >> 2, wn = w & 3;
  const int r0 = lane & 15, kg = lane >> 4;
  const int bid = ((int)blockIdx.x & 7) * 52 + ((int)blockIdx.x >> 3);  // 416 = 8*52
  int grp, tm, tn;
  const bf16 *Ap, *Bp;
  if (bid < 320) { grp = 0; tm = (bid / 20) * 256; tn = (bid % 20) * 256; Ap = xb; Bp = wqkvb; }
  else { grp = 1; int t = bid - 320; tm = (t / 12) * 256; tn = (t % 12) * 256; Ap = qb; Bp = wqlinb; }

  auto stage = [&](int T, int mat, int kh) {
    const bf16* src = mat ? Bp : Ap;
    const int t0 = mat ? tn : tm;
    char* base = (char*)(mat ? (void*)Bs : (void*)As) + (((T & 1) * 2 + kh) << 14);
#pragma unroll
    for (int i = 0; i < 2; i++) {
      int c = i * 512 + tid;
      int row = c >> 2, g = c & 3;
      int sg = (g ^ ((row >> 1) & 3)) * 8;  // pre-swizzled source granule
      gl_lds16(src + (size_t)(t0 + row) * K + T * 64 + kh * 32 + sg, base + c * 16);
    }
  };
  auto ldA = [&](int bi, int kh, int row) -> bf16x8 {
    return *(const bf16x8*)((const char*)As + ((bi * 2 + kh) << 14) + row * 64 +
                            ((kg ^ ((row >> 1) & 3)) << 4));
  };
  auto ldB = [&](int bi, int kh, int row) -> bf16x8 {
    return *(const bf16x8*)((const char*)Bs + ((bi * 2 + kh) << 14) + row * 64 +
                            ((kg ^ ((row >> 1) & 3)) << 4));
  };

  f32x4 acc[8][4] = {};

  stage(0, 0, 0); stage(0, 1, 0); stage(0, 0, 1); stage(0, 1, 1);
  stage(1, 0, 0); stage(1, 1, 0);
  WAITV(4);
  RAW_BAR();

  for (int j = 0; j < NT; ++j) {
    const int bi = j & 1;
    bf16x8 af[4], bfk[4];
    // ---- phase 1: (mh0, kh0)
#pragma unroll
    for (int i = 0; i < 4; i++) af[i] = ldA(bi, 0, wm * 128 + i * 16 + r0);
#pragma unroll
    for (int nf = 0; nf < 4; nf++) bfk[nf] = ldB(bi, 0, wn * 64 + nf * 16 + r0);
    if (j + 1 < NT) stage(j + 1, 0, 1);
    RAW_BAR(); LGKM0(); SCHED0();
    __builtin_amdgcn_s_setprio(1);
#pragma unroll
    for (int i = 0; i < 4; i++)
#pragma unroll
      for (int nf = 0; nf < 4; nf++) acc[i][nf] = MFMA16(af[i], bfk[nf], acc[i][nf]);
    __builtin_amdgcn_s_setprio(0);
    RAW_BAR();
    // ---- phase 2: (mh1, kh0)
#pragma unroll
    for (int i = 0; i < 4; i++) af[i] = ldA(bi, 0, wm * 128 + 64 + i * 16 + r0);
    if (j + 1 < NT) stage(j + 1, 1, 1);
    RAW_BAR(); LGKM0(); SCHED0();
    __builtin_amdgcn_s_setprio(1);
#pragma unroll
    for (int i = 0; i < 4; i++)
#pragma unroll
      for (int nf = 0; nf < 4; nf++) acc[4 + i][nf] = MFMA16(af[i], bfk[nf], acc[4 + i][nf]);
    __builtin_amdgcn_s_setprio(0);
    RAW_BAR();
    // ---- phase 3: (mh0, kh1)
#pragma unroll
    for (int i = 0; i < 4; i++) af[i] = ldA(bi, 1, wm * 128 + i * 16 + r0);
#pragma unroll
    for (int nf = 0; nf < 4; nf++) bfk[nf] = ldB(bi, 1, wn * 64 + nf * 16 + r0);
    if (j + 2 < NT) stage(j + 2, 0, 0);
    RAW_BAR(); LGKM0(); SCHED0();
    __builtin_amdgcn_s_setprio(1);
#pragma unroll
    for (int i = 0; i < 4; i++)
#pragma unroll
      for (int nf = 0; nf < 4; nf++) acc[i][nf] = MFMA16(af[i], bfk[nf], acc[i][nf]);
    __builtin_amdgcn_s_setprio(0);
    RAW_BAR();
    // ---- phase 4: (mh1, kh1)
#pragma unroll
    for (int i = 0; i < 4; i++) af[i] = ldA(bi, 1, wm * 128 + 64 + i * 16 + r0);
    if (j + 2 < NT) stage(j + 2, 1, 0);
    RAW_BAR(); LGKM0(); SCHED0();
    __builtin_amdgcn_s_setprio(1);
#pragma unroll
    for (int i = 0; i < 4; i++)
#pragma unroll
      for (int nf = 0; nf < 4; nf++) acc[4 + i][nf] = MFMA16(af[i], bfk[nf], acc[4 + i][nf]);
    __builtin_amdgcn_s_setprio(0);
    if (j < NT - 2) { WAITV(4); } else { WAITV(0); }
    RAW_BAR();
  }

  // ---------------- epilogue (tn/tm uniform per block; ranges never straddle)
#pragma unroll
  for (int mf = 0; mf < 8; mf++) {
    const int rowb = tm + wm * 128 + mf * 16 + kg * 4;  // 4 consecutive rows (j)
#pragma unroll
    for (int nf = 0; nf < 4; nf++) {
      const int coln = tn + wn * 64 + nf * 16 + r0;
      bool rm; int rmcol = coln, vbase = 0, tokb = 10, rs_ = 3072;
      bf16* vt = VTs;
      bf16* rmp = XK;
      if (grp == 0) {
        if (tn < 2048)      { rm = true; }
        else if (tn < 3072) { rm = false; vbase = 2048; vt = VTs; }
        else if (tn < 4096) { rm = true; rmcol = coln - 1024; }
        else                { rm = false; vbase = 4096; vt = VT0; }
      } else {
        rs_ = 2048; tokb = 9; rmp = QQK;
        if (tn < 2048) { rm = true; }
        else           { rm = false; vbase = 2048; vt = VTq; }
      }
      if (rm) {
#pragma unroll
        for (int j = 0; j < 4; j++)
          rmp[(size_t)(rowb + j) * rs_ + rmcol] = (bf16)acc[mf][nf][j];
      } else {
        int dg = coln - vbase, h_ = dg >> 6, dd = dg & 63;
        int bq = rowb >> tokb, tok = rowb & ((1 << tokb) - 1);
        bf16x4 wv;
#pragma unroll
        for (int j = 0; j < 4; j++) wv[j] = (bf16)acc[mf][nf][j];
        *(bf16x4*)(vt + (((size_t)((bq * 16 + h_) * 64 + dd)) << tokb) + tok) = wv;
      }
    }
  }
}

// ---------------------------------------------------------------- proj GEMM (128x128, proven)
// C[6144,1024] = [xat|qat] x [w_proj|w_qproj]^T + bias, fp32 out to d_out.
__global__ __launch_bounds__(256)
void k_gemm_proj(const bf16* __restrict__ A, const bf16* __restrict__ B0,
                 const bf16* __restrict__ B1, const float* __restrict__ bias0,
                 const float* __restrict__ bias1, float* __restrict__ OUT) {
  constexpr int K = 1024, N = 1024;
  __shared__ bf16 As[128 * 64];
  __shared__ bf16 Bs[128 * 64];
  const int tid = threadIdx.x;
  const int lane = tid & 63, w = tid >> 6;
  const int wr = w >> 1, wc = w & 1;
  const int nbx = N / 128;
  const int bid = ((int)blockIdx.x & 7) * ((int)gridDim.x >> 3) + ((int)blockIdx.x >> 3);
  const int tm = (bid / nbx) * 128, tn = (bid % nbx) * 128;
  const int r0 = lane & 15, kg = lane >> 4;
  const bf16* Bp = (tm < 4096) ? B0 : B1;
  const float* bias = (tm < 4096) ? bias0 : bias1;
  f32x4 acc[4][4] = {};
  for (int kk = 0; kk < K; kk += 64) {
#pragma unroll
    for (int i = 0; i < 4; i++) {
      int c = i * 256 + tid;
      int row = c >> 3, kb = c & 7;
      int sb = (kb ^ ((row ^ (row >> 3)) & 7)) * 8;
      gl_lds16(A + (size_t)(tm + row) * K + kk + sb, (char*)As + c * 16);
      gl_lds16(Bp + (size_t)(tn + row) * K + kk + sb, (char*)Bs + c * 16);
    }
    __syncthreads();
#pragma unroll
    for (int ks = 0; ks < 2; ks++) {
      bf16x8 af[4], bfv[4];
#pragma unroll
      for (int f = 0; f < 4; f++) {
        int rowa = wr * 64 + f * 16 + r0;
        af[f] = *(const bf16x8*)((const char*)As +
                                 ((rowa * 128 + ks * 64 + kg * 16) ^ swz128(rowa)));
        int rowb = wc * 64 + f * 16 + r0;
        bfv[f] = *(const bf16x8*)((const char*)Bs +
                                  ((rowb * 128 + ks * 64 + kg * 16) ^ swz128(rowb)));
      }
#pragma unroll
      for (int mf = 0; mf < 4; mf++)
#pragma unroll
        for (int nf = 0; nf < 4; nf++)
          acc[mf][nf] = MFMA16(af[mf], bfv[nf], acc[mf][nf]);
    }
    __syncthreads();
  }
#pragma unroll
  for (int mf = 0; mf < 4; mf++)
#pragma unroll
    for (int j = 0; j < 4; j++) {
      int row = tm + wr * 64 + mf * 16 + kg * 4 + j;
#pragma unroll
      for (int nf = 0; nf < 4; nf++) {
        int col = tn + wc * 64 + nf * 16 + r0;
        OUT[(size_t)row * 1024 + col] = acc[mf][nf][j] + bias[col];
      }
    }
}

// ---------------------------------------------------------------- flash attention pass (T15)
// Iteration t computes QK^T(t) and PV(t-1) as independent MFMA streams; P(t)
// is packed into registers (pkp) and consumed next iteration. K double-buffer,
// V TRIPLE-buffer (PV lags one tile). One barrier/tile. Online softmax in
// log2-domain, tree reductions, defer-max THR=11.5.
template<int NTH>
__device__ __forceinline__ void attn_pass32(
    const bf16* __restrict__ Kg, int kRS,
    const bf16* __restrict__ VTg, int vRS,
    int ntiles, const bf16x8* qf, bf16* Ks, bf16* Vt,  // Ks:[2][4096], Vt:[3][4096]
    f32x16* o, float& m, float& rs) {
  const int tid = threadIdx.x;
  const int lane = tid & 63;
  const int lq = lane & 31, kg2 = lane >> 5;

  auto stageKV = [&](int t) {
    bf16* kd = Ks + (t & 1) * 4096;
    bf16* vd = Vt + (t % 3) * 4096;
    const bf16* kt = Kg + (size_t)t * 64 * kRS;
#pragma unroll
    for (int i = 0; i < 512 / NTH; i++) {
      int c = i * NTH + tid;
      int r = c >> 3, kb = c & 7;
      int sb = (kb ^ ((r ^ (r >> 3)) & 7)) * 8;  // pre-swizzled source
      gl_lds16(kt + (size_t)r * kRS + sb, (char*)kd + c * 16);
    }
#pragma unroll
    for (int i = 0; i < 512 / NTH; i++) {
      int c = i * NTH + tid;
      int r = c >> 3, kb = c & 7;
      int sb = (kb ^ ((r ^ (r >> 3)) & 7)) * 8;
      gl_lds16(VTg + (size_t)r * vRS + t * 64 + sb, (char*)vd + c * 16);
    }
  };

  unsigned pkp[2][4][2];  // packed P of previous tile

  // QK^T + online softmax + pack -> pkp (pure function of staged K buffer)
  auto qk_softmax = [&](const char* KsC) {
    f32x16 s[2];
    s[0] = (f32x16)0.f; s[1] = (f32x16)0.f;
    __builtin_amdgcn_s_setprio(1);
#pragma unroll
    for (int kb = 0; kb < 2; kb++) {
      int row = kb * 32 + lq;
#pragma unroll
      for (int dw = 0; dw < 4; dw++) {
        bf16x8 kf = *(const bf16x8*)(KsC + ((row * 128 + dw * 32 + kg2 * 16) ^ swz128(row)));
        s[kb] = MFMA32(kf, qf[dw], s[kb]);
      }
    }
    __builtin_amdgcn_s_setprio(0);
    // tree max
    float mm[8];
#pragma unroll
    for (int j = 0; j < 8; j++)
      mm[j] = fmaxf(fmaxf(s[0][j], s[0][j + 8]), fmaxf(s[1][j], s[1][j + 8]));
    float a0 = fmaxf(mm[0], mm[1]), a1 = fmaxf(mm[2], mm[3]);
    float a2 = fmaxf(mm[4], mm[5]), a3 = fmaxf(mm[6], mm[7]);
    float vmax = fmaxf(fmaxf(a0, a1), fmaxf(a2, a3));
    vmax = fmaxf(vmax, __shfl_xor(vmax, 32, 64));
    if (__any(vmax > m + 11.5f)) {  // defer-max (log2 units)
      float mn = fmaxf(m, vmax);
      float fac = exp2_fast(m - mn);
      m = mn;
      rs *= fac;
#pragma unroll
      for (int j = 0; j < 16; j++) {
        int rowq = (j & 3) + 8 * (j >> 2) + 4 * kg2;
        float fj = __shfl(fac, rowq, 64);
        o[0][j] *= fj;
        o[1][j] *= fj;
      }
    }
    float t0 = 0.f, t1 = 0.f, t2 = 0.f, t3 = 0.f;
#pragma unroll
    for (int kb = 0; kb < 2; kb++)
#pragma unroll
      for (int j = 0; j < 16; j += 4) {
        float p0 = exp2_fast(s[kb][j + 0] - m);
        float p1 = exp2_fast(s[kb][j + 1] - m);
        float p2 = exp2_fast(s[kb][j + 2] - m);
        float p3 = exp2_fast(s[kb][j + 3] - m);
        s[kb][j + 0] = p0; s[kb][j + 1] = p1; s[kb][j + 2] = p2; s[kb][j + 3] = p3;
        t0 += p0; t1 += p1; t2 += p2; t3 += p3;
      }
    float tsum = (t0 + t1) + (t2 + t3);
    tsum += __shfl_xor(tsum, 32, 64);
    rs += tsum;
#pragma unroll
    for (int kb = 0; kb < 2; kb++)
#pragma unroll
      for (int n = 0; n < 4; n++) {
        pkp[kb][n][0] = pack2(s[kb][4 * n + 0], s[kb][4 * n + 1]);
        pkp[kb][n][1] = pack2(s[kb][4 * n + 2], s[kb][4 * n + 3]);
      }
  };

  // PV using pkp (previous tile's P) against a staged V^T buffer
  auto pv = [&](const char* VtC) {
#pragma unroll
    for (int w = 0; w < 4; w++) {
      const int kb = w >> 1, wb = w & 1;
      unsigned pushA = kg2 ? pkp[kb][2 * wb][0] : pkp[kb][2 * wb + 1][0];
      unsigned pushB = kg2 ? pkp[kb][2 * wb][1] : pkp[kb][2 * wb + 1][1];
      unsigned rcvA = __shfl_xor(pushA, 32, 64);
      unsigned rcvB = __shfl_xor(pushB, 32, 64);
      u32x4 fu;
      fu[0] = kg2 ? rcvA : pkp[kb][2 * wb][0];
      fu[1] = kg2 ? rcvB : pkp[kb][2 * wb][1];
      fu[2] = kg2 ? pkp[kb][2 * wb + 1][0] : rcvA;
      fu[3] = kg2 ? pkp[kb][2 * wb + 1][1] : rcvB;
      bf16x8 pfrag = __builtin_bit_cast(bf16x8, fu);
      __builtin_amdgcn_s_setprio(1);
#pragma unroll
      for (int db = 0; db < 2; db++) {
        int d = db * 32 + lq;
        bf16x8 vf = *(const bf16x8*)(VtC + ((d * 128 + w * 32 + kg2 * 16) ^ swz128(d)));
        o[db] = MFMA32(pfrag, vf, o[db]);
      }
      __builtin_amdgcn_s_setprio(0);
    }
  };

  RAW_BAR();  // entry: previous pass (if any) done reading this LDS
  stageKV(0);
  if (ntiles > 1) { stageKV(1); WAITV(4); } else { WAITV(0); }
  RAW_BAR();
  // tile 0: QK + softmax only (PV deferred)
  qk_softmax((const char*)(Ks + 0));

  for (int t = 1; t < ntiles; t++) {
    WAITV(0);   // stage(t) (issued last iteration) fully landed
    RAW_BAR();  // ...visible to all waves; all waves done with body(t-1) reads
    if (t + 1 < ntiles) stageKV(t + 1);  // overwrites Ks[(t-1)&1], Vt[(t+1)%3] (free)
    // body: QK(t) and PV(t-1) are independent MFMA streams (scheduler interleaves);
    // softmax(t) overlaps PV's shadow; rescale (rare) depends on o after PV lands.
    const char* KsC = (const char*)(Ks + (t & 1) * 4096);
    const char* VtP = (const char*)(Vt + ((t - 1) % 3) * 4096);
    pv(VtP);           // consumes pkp(t-1)
    qk_softmax(KsC);   // produces pkp(t); s-dep places it after QK MFMAs
  }
  // epilogue: PV of last tile
  pv((const char*)(Vt + ((ntiles - 1) % 3) * 4096));
}

// ---------------------------------------------------------------- merged attention
// grid = 768 blocks. XCD-PROPORTIONAL mapping: each XCD chunk of 96 blocks =
// 64 self (16 KV tiles) + 32 cross (8 tiles, gate=0 path), so per-XCD work is
// balanced (40 tiles/CU avg vs 48 worst-case under contiguous chunking).
// bid [0,512) self (bh = bid>>3, qtile = bid&7); [512,768) cross.
// XK[4096][3072]: cols q|k|xk0. QQK[2048][2048]: cols qq|qk.
// VTs/VT0: [bh][64][1024]; VTq: [bh][64][512].
__global__ __launch_bounds__(256)
void k_attn(const bf16* __restrict__ XK, const bf16* __restrict__ QQK,
            const bf16* __restrict__ VTs, const bf16* __restrict__ VT0,
            const bf16* __restrict__ VTq, const float* __restrict__ gate,
            bf16* __restrict__ xat, bf16* __restrict__ qat) {
  __shared__ bf16 Ks[2 * 4096], Vt[3 * 4096];
  const int pb = blockIdx.x;
  const int xcd = pb & 7, pos = pb >> 3;  // pos in [0,96)
  const int bid = (pos < 64) ? (xcd * 64 + pos)             // self: [0,512)
                             : (512 + xcd * 32 + (pos - 64)); // cross: [512,768)
  const int tid = threadIdx.x, lane = tid & 63, wv = tid >> 6;
  const int lq = lane & 31, kg2 = lane >> 5;
  constexpr float QS = 0.125f * 1.44269504088896f;  // scale * log2(e)

  if (bid < 512) {
    // ---------------- self attention
    const int bh = bid >> 3, r = bid & 7;
    const int b = bh >> 4, h = bh & 15;
    const int qtok = b * 1024 + r * 128 + wv * 32;
    bf16x8 qf[4];
#pragma unroll
    for (int dw = 0; dw < 4; dw++) {
      qf[dw] = *(const bf16x8*)(XK + (size_t)(qtok + lq) * 3072 + h * 64 + dw * 16 + kg2 * 8);
#pragma unroll
      for (int e = 0; e < 8; e++) qf[dw][e] = (bf16)((float)qf[dw][e] * QS);
    }
    f32x16 o[2];
    o[0] = (f32x16)0.f; o[1] = (f32x16)0.f;
    float m = -__builtin_inff(), rs = 0.f;
    attn_pass32<256>(XK + (size_t)(b * 1024) * 3072 + 1024 + h * 64, 3072,
                     VTs + (size_t)bh * 64 * 1024, 1024,
                     16, qf, Ks, Vt, o, m, rs);
#pragma unroll
    for (int j = 0; j < 16; j++) {
      int rowq = (j & 3) + 8 * (j >> 2) + 4 * kg2;
      float rsj = __shfl(rs, rowq, 64);
      size_t base = (size_t)(qtok + rowq) * 1024 + h * 64;
      xat[base + lq] = (bf16)(o[0][j] / rsj);
      xat[base + 32 + lq] = (bf16)(o[1][j] / rsj);
    }
  } else {
    // ---------------- cross attention
    const int c = bid - 512;
    const int bh = c >> 2, qt = c & 3;
    const int b = bh >> 4, h = bh & 15;
    const int qtok = b * 512 + qt * 128 + wv * 32;
    bf16x8 qf[4];
#pragma unroll
    for (int dw = 0; dw < 4; dw++) {
      qf[dw] = *(const bf16x8*)(QQK + (size_t)(qtok + lq) * 2048 + h * 64 + dw * 16 + kg2 * 8);
#pragma unroll
      for (int e = 0; e < 8; e++) qf[dw][e] = (bf16)((float)qf[dw][e] * QS);
    }
    const float g = tanhf(gate[h]);  // block-uniform (zero-init param -> skip seg A)
    unsigned pka[2][8] = {};         // packed g*softmax(QK0)V0 result (seg A)
    f32x16 o[2];
    o[0] = (f32x16)0.f; o[1] = (f32x16)0.f;
    float m, rs;
    if (g != 0.0f) {
      m = -__builtin_inff(); rs = 0.f;
      attn_pass32<256>(XK + (size_t)(b * 1024) * 3072 + 2048 + h * 64, 3072,
                       VT0 + (size_t)bh * 64 * 1024, 1024,
                       16, qf, Ks, Vt, o, m, rs);
#pragma unroll
      for (int j2 = 0; j2 < 8; j2++) {
        int j0 = 2 * j2;
        int rq0 = (j0 & 3) + 8 * (j0 >> 2) + 4 * kg2;  // rq1 = rq0 + 1
        float ra = __shfl(rs, rq0, 64);
        float rb = __shfl(rs, rq0 + 1, 64);
        pka[0][j2] = pack2(g * o[0][j0] / ra, g * o[0][j0 + 1] / rb);
        pka[1][j2] = pack2(g * o[1][j0] / ra, g * o[1][j0 + 1] / rb);
      }
      o[0] = (f32x16)0.f; o[1] = (f32x16)0.f;
    }
    m = -__builtin_inff(); rs = 0.f;
    attn_pass32<256>(QQK + (size_t)(b * 512) * 2048 + 1024 + h * 64, 2048,
                     VTq + (size_t)bh * 64 * 512, 512,
                     8, qf, Ks, Vt, o, m, rs);
#pragma unroll
    for (int j = 0; j < 16; j++) {
      int rowq = (j & 3) + 8 * (j >> 2) + 4 * kg2;
      float rsj = __shfl(rs, rowq, 64);
      size_t base = (size_t)(qtok + rowq) * 1024 + h * 64;
      unsigned wa = pka[0][j >> 1], wb = pka[1][j >> 1];
      unsigned short ua = (j & 1) ? (unsigned short)(wa >> 16) : (unsigned short)(wa & 0xffffu);
      unsigned short ub = (j & 1) ? (unsigned short)(wb >> 16) : (unsigned short)(wb & 0xffffu);
      float a0 = (float)__builtin_bit_cast(bf16, ua);
      float a1 = (float)__builtin_bit_cast(bf16, ub);
      qat[base + lq] = (bf16)(o[0][j] / rsj + a0);
      qat[base + 32 + lq] = (bf16)(o[1][j] / rsj + a1);
    }
  }
}

// ---------------------------------------------------------------- launch
extern "C" void kernel_launch(void* const* d_in, const int* in_sizes, int n_in,
                              void* d_out, int out_size, void* d_ws, size_t ws_size,
                              hipStream_t stream) {
  (void)in_sizes; (void)n_in; (void)out_size; (void)ws_size;
  const float* x       = (const float*)d_in[0];
  const float* query   = (const float*)d_in[1];
  const float* w_qkv   = (const float*)d_in[2];
  const float* w_kv    = (const float*)d_in[3];
  const float* w_qlin  = (const float*)d_in[4];
  const float* gate    = (const float*)d_in[5];
  const float* w_proj  = (const float*)d_in[6];
  const float* b_proj  = (const float*)d_in[7];
  const float* w_qproj = (const float*)d_in[8];
  const float* b_qproj = (const float*)d_in[9];
  float* out = (float*)d_out;

  bf16* p = (bf16*)d_ws;
  bf16* xb = p;      p += (size_t)4096 * 1024;   // 4M @ 0
  bf16* qb = p;      p += (size_t)2048 * 1024;   // 2M @ 4M
  bf16* wqkvb = p;   p += (size_t)3072 * 1024;   // 3M @ 6M (adjacent to wkvb)
  bf16* wkvb = p;    p += (size_t)2048 * 1024;   // 2M @ 9M
  bf16* wqlinb = p;  p += (size_t)3072 * 1024;   // 3M @ 11M
  bf16* wprojb = p;  p += (size_t)1024 * 1024;   // 1M @ 14M
  bf16* wqprojb = p; p += (size_t)1024 * 1024;   // 1M @ 15M
  bf16* XK = p;      p += (size_t)4096 * 3072;   // q|k|xk0 row-major
  bf16* VTs = p;     p += (size_t)64 * 64 * 1024; // self V^T
  bf16* VT0 = p;     p += (size_t)64 * 64 * 1024; // xv0 V^T
  bf16* QQK = p;     p += (size_t)2048 * 2048;   // qq|qk row-major
  bf16* VTq = p;     p += (size_t)64 * 64 * 512;  // qv V^T
  bf16* xat = p;     p += (size_t)4096 * 1024;   // (xat, qat adjacent -> proj A)
  bf16* qat = p;     p += (size_t)2048 * 1024;
  (void)wkvb;

  k_cast_all<<<2048, 256, 0, stream>>>(x, query, w_qkv, w_kv, w_qlin, w_proj, w_qproj,
                                       (bf16*)d_ws);

  // grouped big GEMM: XKV (320 blocks) + qlin (96 blocks), 8-phase schedule
  k_gemm_big<<<dim3(416), 512, 0, stream>>>(xb, qb, wqkvb, wqlinb,
                                            XK, VTs, VT0, QQK, VTq);

  k_attn<<<dim3(768), 256, 0, stream>>>(XK, QQK, VTs, VT0, VTq, gate, xat, qat);

  // fused output projections: A = [xat|qat] (6144x1024)
  k_gemm_proj<<<dim3(48 * 8), 256, 0, stream>>>(xat, wprojb, wqprojb, b_proj, b_qproj, out);
}